// Round 7
// baseline (635.568 us; speedup 1.0000x reference)
//
#include <hip/hip_runtime.h>

#define D 64          // D_IN == D_OUT
#define D_EDGE 16
#define NEG 0.01f

typedef unsigned int   uint32;
typedef unsigned short u16;

__device__ __forceinline__ float leaky(float v) { return v > 0.f ? v : NEG * v; }

// fp32 -> bf16 (round-to-nearest-even), and back (exact)
__device__ __forceinline__ u16 f2bf(float f) {
    uint32 b = __float_as_uint(f);
    uint32 r = b + 0x7fffu + ((b >> 16) & 1u);
    return (u16)(r >> 16);
}
__device__ __forceinline__ float bf2f(u16 u) {
    return __uint_as_float(((uint32)u) << 16);
}

// DPP-based cross-lane add: v += dpp_move(v, ctrl), invalid lanes contribute 0.
// row_shr:N = 0x110|N, row_bcast15 = 0x142, row_bcast31 = 0x143
#define DPP_ADD(v, ctrl)                                                       \
    v += __int_as_float(__builtin_amdgcn_update_dpp(                           \
            0, __float_as_int(v), ctrl, 0xf, 0xf, true))

__device__ __forceinline__ float readlane_f(float v, int l) {
    return __int_as_float(__builtin_amdgcn_readlane(__float_as_int(v), l));
}

// ---------------- Kernel 1: per-node precompute, lane = channel -------------
//   xt[n][k] (bf16) = x[n]·W2[k,:] ; A[n][k] (bf16) = x[n]·W1[k,0:64]
//   r[n] = sum_j leaky(x[n][j]) * attn[64+j]
// Weight row k lives in lane k's registers (staged via padded LDS transpose).
// Node loop is wave-uniform -> x row arrives via scalar loads feeding v_fma.
__global__ __launch_bounds__(256, 2) void node_kernel(
    const float* __restrict__ x, const float* __restrict__ W1,
    const float* __restrict__ W2, const float* __restrict__ attn,
    u16* __restrict__ Abf, u16* __restrict__ xtb, float* __restrict__ r,
    int N_, int nodes_per_wave)
{
    __shared__ float w2s[64 * 65];
    __shared__ float w1s[64 * 65];
    for (int i = threadIdx.x; i < 64 * 64; i += 256) {
        int k = i >> 6, j = i & 63;
        w2s[k * 65 + j] = W2[i];              // coalesced read, conflict-free write
        w1s[k * 65 + j] = W1[k * 80 + j];
    }
    __syncthreads();

    const int lane = threadIdx.x & 63;
    float w2r[64], w1r[64];
#pragma unroll
    for (int j = 0; j < 64; j++) {            // bank = (lane+j)%32 -> conflict-free
        w2r[j] = w2s[lane * 65 + j];
        w1r[j] = w1s[lane * 65 + j];
    }
    const float ahl = attn[64 + lane];

    const int wave = blockIdx.x * 4 + (threadIdx.x >> 6);
    int n  = wave * nodes_per_wave;
    int nE = n + nodes_per_wave; if (nE > N_) nE = N_;

    for (; n < nE; n++) {
        const int nu = __builtin_amdgcn_readfirstlane(n);
        const float* xrow = x + (size_t)nu * D;
        float a2 = 0.f, a1 = 0.f;
#pragma unroll
        for (int j = 0; j < 64; j++) {
            float xj = xrow[j];               // uniform address -> s_load
            a2 = fmaf(xj, w2r[j], a2);
            a1 = fmaf(xj, w1r[j], a1);
        }
        xtb[(size_t)nu * D + lane] = f2bf(a2);   // 2B/lane coalesced
        Abf[(size_t)nu * D + lane] = f2bf(a1);

        float t = leaky(xrow[lane]) * ahl;       // vector load, row is L1-hot
        DPP_ADD(t, 0x111); DPP_ADD(t, 0x112); DPP_ADD(t, 0x114); DPP_ADD(t, 0x118);
        DPP_ADD(t, 0x142); DPP_ADD(t, 0x143);    // lane63 = full 64-lane sum
        if (lane == 0) r[nu] = readlane_f(t, 63);
    }
}

// ---------------- Kernel 2: fused edge kernel ------------------------------
// Half-wave per edge (2 edges/wave-iter), DPP reduce (no DS ops), 1-deep
// software pipeline: iteration i+1's gathers are issued before computing i.
__global__ __launch_bounds__(256) void edge_kernel(
    const float* __restrict__ edge_attr, const int* __restrict__ src,
    const int* __restrict__ dst, const float* __restrict__ W1,
    const float* __restrict__ attn,
    const u16* __restrict__ Abf, const u16* __restrict__ xtb,
    const float* __restrict__ r,
    float* __restrict__ out, float* __restrict__ denom,
    int E_, int chunk)
{
    const int lane = threadIdx.x & 63;
    const int half = lane >> 5;
    const int k0   = (lane & 31) * 2;

    const float4* w1p = (const float4*)(W1 + k0 * 80 + 64);
    float4 wa0 = w1p[0], wa1 = w1p[1], wa2 = w1p[2], wa3 = w1p[3];
    const float4* w1q = (const float4*)(W1 + (k0 + 1) * 80 + 64);
    float4 wb0 = w1q[0], wb1 = w1q[1], wb2 = w1q[2], wb3 = w1q[3];
    float ak0 = attn[k0], ak1 = attn[k0 + 1];

    const uint32* Au = (const uint32*)Abf;   // packed bf16x2, dword idx = s*32 + k0/2

    const int wave   = blockIdx.x * 4 + (threadIdx.x >> 6);
    const int npairs = E_ >> 1;
    int pr = wave * chunk;
    int pe = pr + chunk; if (pe > npairs) pe = npairs;

    if (pr < pe) {
        // ---- prologue: stage iteration pr ----
        int e0 = pr * 2;
        int2 ss = *(const int2*)(src + e0);
        int2 dd = *(const int2*)(dst + e0);
        int sh = half ? ss.y : ss.x;
        uint32 av = Au[(size_t)sh * 32 + (lane & 31)];
        const float4* eap = (const float4*)(edge_attr + (size_t)(e0 + half) * D_EDGE);
        float4 q0 = eap[0], q1 = eap[1], q2 = eap[2], q3 = eap[3];
        float rA = r[dd.x], rB = r[dd.y];
        u16 mAu = xtb[(size_t)ss.x * D + lane];
        u16 mBu = xtb[(size_t)ss.y * D + lane];

        while (true) {
            const int prn = pr + 1;
            const bool hn = prn < pe;
            int2 ss2, dd2; uint32 av2 = 0;
            float4 n0, n1, n2, n3; float rA2 = 0.f, rB2 = 0.f;
            u16 mA2 = 0, mB2 = 0;
            if (hn) {
                // ---- issue next iteration's loads before current compute ----
                int e1 = prn * 2;
                ss2 = *(const int2*)(src + e1);
                dd2 = *(const int2*)(dst + e1);
                int sh2 = half ? ss2.y : ss2.x;
                av2 = Au[(size_t)sh2 * 32 + (lane & 31)];
                const float4* ep2 = (const float4*)(edge_attr + (size_t)(e1 + half) * D_EDGE);
                n0 = ep2[0]; n1 = ep2[1]; n2 = ep2[2]; n3 = ep2[3];
                rA2 = r[dd2.x]; rB2 = r[dd2.y];
                mA2 = xtb[(size_t)ss2.x * D + lane];
                mB2 = xtb[(size_t)ss2.y * D + lane];
            }

            // ---- compute current ----
            float a0 = bf2f((u16)(av & 0xffffu));
            float a1 = bf2f((u16)(av >> 16));
            float g0 = q0.x*wa0.x + q0.y*wa0.y + q0.z*wa0.z + q0.w*wa0.w
                     + q1.x*wa1.x + q1.y*wa1.y + q1.z*wa1.z + q1.w*wa1.w
                     + q2.x*wa2.x + q2.y*wa2.y + q2.z*wa2.z + q2.w*wa2.w
                     + q3.x*wa3.x + q3.y*wa3.y + q3.z*wa3.z + q3.w*wa3.w;
            float g1 = q0.x*wb0.x + q0.y*wb0.y + q0.z*wb0.z + q0.w*wb0.w
                     + q1.x*wb1.x + q1.y*wb1.y + q1.z*wb1.z + q1.w*wb1.w
                     + q2.x*wb2.x + q2.y*wb2.y + q2.z*wb2.z + q2.w*wb2.w
                     + q3.x*wb3.x + q3.y*wb3.y + q3.z*wb3.z + q3.w*wb3.w;
            float v = leaky(a0 + g0) * ak0 + leaky(a1 + g1) * ak1;

            // DPP reduce: lane31 = sum(half0), lane63 = sum(half1)
            DPP_ADD(v, 0x111); DPP_ADD(v, 0x112); DPP_ADD(v, 0x114); DPP_ADD(v, 0x118);
            DPP_ADD(v, 0x142);
            float sA = readlane_f(v, 31);
            float sB = readlane_f(v, 63);

            float pA = __expf(sA + rA);
            float pB = __expf(sB + rB);
            atomicAdd(out + (size_t)dd.x * D + lane, pA * bf2f(mAu));
            atomicAdd(out + (size_t)dd.y * D + lane, pB * bf2f(mBu));
            if (lane == 0)       atomicAdd(denom + dd.x, pA);
            else if (lane == 32) atomicAdd(denom + dd.y, pB);

            if (!hn) break;
            // ---- rotate pipeline registers ----
            ss = ss2; dd = dd2; av = av2;
            q0 = n0; q1 = n1; q2 = n2; q3 = n3;
            rA = rA2; rB = rB2; mAu = mA2; mBu = mB2;
            pr = prn;
        }
    }

    // tail: odd E_ (not hit at E=1.28M, kept for correctness)
    if (wave == 0 && (E_ & 1)) {
        int e = E_ - 1;
        int s = src[e], d = dst[e];
        uint32 av = Au[(size_t)s * 32 + (lane & 31)];
        float a0 = bf2f((u16)(av & 0xffffu));
        float a1 = bf2f((u16)(av >> 16));
        const float4* eap = (const float4*)(edge_attr + (size_t)e * D_EDGE);
        float4 q0 = eap[0], q1 = eap[1], q2 = eap[2], q3 = eap[3];
        float g0 = q0.x*wa0.x + q0.y*wa0.y + q0.z*wa0.z + q0.w*wa0.w
                 + q1.x*wa1.x + q1.y*wa1.y + q1.z*wa1.z + q1.w*wa1.w
                 + q2.x*wa2.x + q2.y*wa2.y + q2.z*wa2.z + q2.w*wa2.w
                 + q3.x*wa3.x + q3.y*wa3.y + q3.z*wa3.z + q3.w*wa3.w;
        float g1 = q0.x*wb0.x + q0.y*wb0.y + q0.z*wb0.z + q0.w*wb0.w
                 + q1.x*wb1.x + q1.y*wb1.y + q1.z*wb1.z + q1.w*wb1.w
                 + q2.x*wb2.x + q2.y*wb2.y + q2.z*wb2.z + q2.w*wb2.w
                 + q3.x*wb3.x + q3.y*wb3.y + q3.z*wb3.z + q3.w*wb3.w;
        float v = leaky(a0 + g0) * ak0 + leaky(a1 + g1) * ak1;
        DPP_ADD(v, 0x111); DPP_ADD(v, 0x112); DPP_ADD(v, 0x114); DPP_ADD(v, 0x118);
        DPP_ADD(v, 0x142); DPP_ADD(v, 0x143);
        float p = __expf(readlane_f(v, 63) + r[d]);
        atomicAdd(out + (size_t)d * D + lane, p * bf2f(xtb[(size_t)s * D + lane]));
        if (lane == 0) atomicAdd(denom + d, p);
    }
}

// ---------------- Kernel 3: normalize + bias ----------------
__global__ __launch_bounds__(256) void fin_kernel(
    float* __restrict__ out, const float* __restrict__ denom,
    const float* __restrict__ bias, int total)
{
    int i = blockIdx.x * 256 + threadIdx.x;
    if (i >= total) return;
    int n = i >> 6, k = i & 63;
    float dn = denom[n];
    float sc = dn > 0.f ? 1.f / dn : 0.f;
    out[i] = fmaf(out[i], sc, bias[k]);
}

extern "C" void kernel_launch(void* const* d_in, const int* in_sizes, int n_in,
                              void* d_out, int out_size, void* d_ws, size_t ws_size,
                              hipStream_t stream)
{
    const float* x         = (const float*)d_in[0];
    const float* edge_attr = (const float*)d_in[1];
    const int*   src       = (const int*)d_in[2];
    const int*   dst       = (const int*)d_in[3];
    const float* W1        = (const float*)d_in[4];
    const float* W2        = (const float*)d_in[5];
    const float* attn      = (const float*)d_in[6];
    const float* bias      = (const float*)d_in[7];
    float* out = (float*)d_out;

    const int N_ = in_sizes[0] / D;   // 100000
    const int E_ = in_sizes[2];       // 1280000

    // workspace: Abf[N*64] bf16 | xtb[N*64] bf16 | r[N] f32 | denom[N] f32
    u16*   Abf   = (u16*)d_ws;
    u16*   xtb   = Abf + (size_t)N_ * D;
    float* r     = (float*)(xtb + (size_t)N_ * D);
    float* denom = r + N_;

    hipMemsetAsync(out,   0, (size_t)out_size * sizeof(float), stream);
    hipMemsetAsync(denom, 0, (size_t)N_ * sizeof(float), stream);

    const int nBlocks = 512;                      // 2048 waves
    const int npw     = (N_ + 2047) / 2048;       // nodes per wave
    node_kernel<<<nBlocks, 256, 0, stream>>>(x, W1, W2, attn, Abf, xtb, r, N_, npw);

    const int eBlocks = 8192;
    const int nwaves  = eBlocks * 4;
    const int npairs  = E_ >> 1;
    const int chunk   = (npairs + nwaves - 1) / nwaves;
    edge_kernel<<<eBlocks, 256, 0, stream>>>(edge_attr, src, dst, W1, attn,
                                             Abf, xtb, r, out, denom, E_, chunk);

    fin_kernel<<<((size_t)N_ * D + 255) / 256, 256, 0, stream>>>(out, denom, bias, N_ * D);
}

// Round 8
// 554.731 us; speedup vs baseline: 1.1457x; 1.1457x over previous
//
#include <hip/hip_runtime.h>

#define D 64          // D_IN == D_OUT
#define D_EDGE 16
#define NEG 0.01f

typedef unsigned int   uint32;
typedef unsigned short u16;

__device__ __forceinline__ float leaky(float v) { return v > 0.f ? v : NEG * v; }

// fp32 -> bf16 (round-to-nearest-even), and back (exact)
__device__ __forceinline__ u16 f2bf(float f) {
    uint32 b = __float_as_uint(f);
    uint32 r = b + 0x7fffu + ((b >> 16) & 1u);
    return (u16)(r >> 16);
}
__device__ __forceinline__ float bf2f(u16 u) {
    return __uint_as_float(((uint32)u) << 16);
}

// ---------------- Kernel 1: node GEMM, register-tiled ----------------------
// C[n][o] = x[n]·Wstk[:,o], o in [0,128): o<64 -> xt (W2), o>=64 -> A (W1a).
// Block: 128 nodes x 128 outs, 256 threads, thread tile 8x8.
// tn = tid>>4 (8 nodes), to = tid&15 (8 outs) -> wave = 4 tn x 16 to, so the
// x-read has at most 4 distinct LDS addrs/instr and w-read 4-way banks.
__global__ __launch_bounds__(256, 2) void node_kernel(
    const float* __restrict__ x, const float* __restrict__ W1,
    const float* __restrict__ W2,
    u16* __restrict__ Abf, u16* __restrict__ xtb, int N_)
{
    __shared__ float xs[128][68];   // pad 68: float4-aligned staging, low conflicts
    __shared__ float ws[64][132];   // ws[j][o], pad 132 keeps 16B alignment

    const int tid = threadIdx.x;
    const int nb  = blockIdx.x * 128;

    // ---- stage x tile: 128 rows x 64 cols, float4 coalesced ----
    {
        const float4* xg = (const float4*)x;
#pragma unroll
        for (int k = 0; k < 8; k++) {
            int f    = tid + k * 256;      // float4 index in tile [0,2048)
            int row  = f >> 4;
            int col4 = f & 15;
            int n    = nb + row;
            float4 v = (n < N_) ? xg[(size_t)n * 16 + col4]
                                : make_float4(0.f, 0.f, 0.f, 0.f);
            *(float4*)&xs[row][col4 * 4] = v;
        }
    }
    // ---- stage stacked weights: ws[j][o] ----
    {
#pragma unroll
        for (int k = 0; k < 32; k++) {
            int f = tid + k * 256;         // [0, 8192)
            int o = f & 127, j = f >> 7;
            float w = (o < 64) ? W2[o * 64 + j] : W1[(o - 64) * 80 + j];
            ws[j][o] = w;
        }
    }
    __syncthreads();

    const int tn = tid >> 4;               // node sub-tile
    const int to = tid & 15;               // out sub-tile
    const int n0 = tn * 8;
    const int o0 = to * 8;

    float acc[8][8];
#pragma unroll
    for (int i = 0; i < 8; i++)
#pragma unroll
        for (int c = 0; c < 8; c++) acc[i][c] = 0.f;

#pragma unroll 4
    for (int j = 0; j < 64; j++) {
        float xv[8];
#pragma unroll
        for (int i = 0; i < 8; i++) xv[i] = xs[n0 + i][j];
        float4 wv0 = *(const float4*)&ws[j][o0];
        float4 wv1 = *(const float4*)&ws[j][o0 + 4];
        float wv[8] = {wv0.x, wv0.y, wv0.z, wv0.w, wv1.x, wv1.y, wv1.z, wv1.w};
#pragma unroll
        for (int i = 0; i < 8; i++)
#pragma unroll
            for (int c = 0; c < 8; c++)
                acc[i][c] = fmaf(xv[i], wv[c], acc[i][c]);
    }

    // ---- store: pack 8 bf16 per node into uint4 ----
    u16* dstbase = (to < 8) ? xtb : Abf;
    const int oo = (o0 & 63);
#pragma unroll
    for (int i = 0; i < 8; i++) {
        int n = nb + n0 + i;
        if (n >= N_) break;
        uint32 d0 = (uint32)f2bf(acc[i][0]) | ((uint32)f2bf(acc[i][1]) << 16);
        uint32 d1 = (uint32)f2bf(acc[i][2]) | ((uint32)f2bf(acc[i][3]) << 16);
        uint32 d2 = (uint32)f2bf(acc[i][4]) | ((uint32)f2bf(acc[i][5]) << 16);
        uint32 d3 = (uint32)f2bf(acc[i][6]) | ((uint32)f2bf(acc[i][7]) << 16);
        uint4 pk = make_uint4(d0, d1, d2, d3);
        *(uint4*)(dstbase + (size_t)n * D + oo) = pk;
    }
}

// ---------------- Kernel 1b: r[n] = sum_j leaky(x[n][j])*attn[64+j] --------
__global__ __launch_bounds__(256) void r_kernel(
    const float* __restrict__ x, const float* __restrict__ attn,
    float* __restrict__ r, int N_)
{
    const int lane = threadIdx.x & 63;
    const int wave = blockIdx.x * 4 + (threadIdx.x >> 6);
    const int nw   = gridDim.x * 4;
    const float ahl = attn[64 + lane];

    for (int n = wave; n < N_; n += nw) {
        float t = leaky(x[(size_t)n * D + lane]) * ahl;
#pragma unroll
        for (int off = 32; off > 0; off >>= 1) t += __shfl_xor(t, off, 64);
        if (lane == 0) r[n] = t;
    }
}

// ---------------- Kernel 2: fused edge kernel (R6 verbatim) ----------------
// Half-wave per edge (2 edges/wave-iter), bf16 A/xt gathers, fp32 atomics.
__global__ __launch_bounds__(256) void edge_kernel(
    const float* __restrict__ edge_attr, const int* __restrict__ src,
    const int* __restrict__ dst, const float* __restrict__ W1,
    const float* __restrict__ attn,
    const u16* __restrict__ Abf, const u16* __restrict__ xtb,
    const float* __restrict__ r,
    float* __restrict__ out, float* __restrict__ denom,
    int E_, int chunk)
{
    const int lane = threadIdx.x & 63;
    const int half = lane >> 5;
    const int k0   = (lane & 31) * 2;

    const float4* w1p = (const float4*)(W1 + k0 * 80 + 64);
    float4 wa0 = w1p[0], wa1 = w1p[1], wa2 = w1p[2], wa3 = w1p[3];
    const float4* w1q = (const float4*)(W1 + (k0 + 1) * 80 + 64);
    float4 wb0 = w1q[0], wb1 = w1q[1], wb2 = w1q[2], wb3 = w1q[3];
    float ak0 = attn[k0], ak1 = attn[k0 + 1];

    const uint32* Au = (const uint32*)Abf;   // packed bf16x2, dword idx = s*32 + k0/2

    const int wave   = blockIdx.x * 4 + (threadIdx.x >> 6);
    const int npairs = E_ >> 1;
    int pr  = wave * chunk;
    int pe  = pr + chunk; if (pe > npairs) pe = npairs;

    for (; pr < pe; pr++) {
        const int e0 = pr * 2;
        int2 ss = *(const int2*)(src + e0);
        int2 dd = *(const int2*)(dst + e0);

        int s_h = half ? ss.y : ss.x;
        uint32 av = Au[(size_t)s_h * 32 + (lane & 31)];
        float a0 = bf2f((u16)(av & 0xffffu));
        float a1 = bf2f((u16)(av >> 16));

        const float4* eap = (const float4*)(edge_attr + (size_t)(e0 + half) * D_EDGE);
        float4 q0 = eap[0], q1 = eap[1], q2 = eap[2], q3 = eap[3];

        float g0 = q0.x*wa0.x + q0.y*wa0.y + q0.z*wa0.z + q0.w*wa0.w
                 + q1.x*wa1.x + q1.y*wa1.y + q1.z*wa1.z + q1.w*wa1.w
                 + q2.x*wa2.x + q2.y*wa2.y + q2.z*wa2.z + q2.w*wa2.w
                 + q3.x*wa3.x + q3.y*wa3.y + q3.z*wa3.z + q3.w*wa3.w;
        float g1 = q0.x*wb0.x + q0.y*wb0.y + q0.z*wb0.z + q0.w*wb0.w
                 + q1.x*wb1.x + q1.y*wb1.y + q1.z*wb1.z + q1.w*wb1.w
                 + q2.x*wb2.x + q2.y*wb2.y + q2.z*wb2.z + q2.w*wb2.w
                 + q3.x*wb3.x + q3.y*wb3.y + q3.z*wb3.z + q3.w*wb3.w;

        float v = leaky(a0 + g0) * ak0 + leaky(a1 + g1) * ak1;

#pragma unroll
        for (int off = 16; off > 0; off >>= 1) v += __shfl_xor(v, off, 64);
        float vo = __shfl_xor(v, 32, 64);
        float vA = half ? vo : v;
        float vB = half ? v : vo;

        float pA = __expf(vA + r[dd.x]);
        float pB = __expf(vB + r[dd.y]);

        float mA = bf2f(xtb[(size_t)ss.x * D + lane]);
        float mB = bf2f(xtb[(size_t)ss.y * D + lane]);
        atomicAdd(out + (size_t)dd.x * D + lane, pA * mA);
        atomicAdd(out + (size_t)dd.y * D + lane, pB * mB);
        if (lane == 0)       atomicAdd(denom + dd.x, pA);
        else if (lane == 32) atomicAdd(denom + dd.y, pB);
    }

    if (wave == 0 && (E_ & 1)) {
        int e = E_ - 1;
        int s = src[e], d = dst[e];
        uint32 av = Au[(size_t)s * 32 + (lane & 31)];
        float a0 = bf2f((u16)(av & 0xffffu));
        float a1 = bf2f((u16)(av >> 16));
        const float4* eap = (const float4*)(edge_attr + (size_t)e * D_EDGE);
        float4 q0 = eap[0], q1 = eap[1], q2 = eap[2], q3 = eap[3];
        float g0 = q0.x*wa0.x + q0.y*wa0.y + q0.z*wa0.z + q0.w*wa0.w
                 + q1.x*wa1.x + q1.y*wa1.y + q1.z*wa1.z + q1.w*wa1.w
                 + q2.x*wa2.x + q2.y*wa2.y + q2.z*wa2.z + q2.w*wa2.w
                 + q3.x*wa3.x + q3.y*wa3.y + q3.z*wa3.z + q3.w*wa3.w;
        float g1 = q0.x*wb0.x + q0.y*wb0.y + q0.z*wb0.z + q0.w*wb0.w
                 + q1.x*wb1.x + q1.y*wb1.y + q1.z*wb1.z + q1.w*wb1.w
                 + q2.x*wb2.x + q2.y*wb2.y + q2.z*wb2.z + q2.w*wb2.w
                 + q3.x*wb3.x + q3.y*wb3.y + q3.z*wb3.z + q3.w*wb3.w;
        float v = leaky(a0 + g0) * ak0 + leaky(a1 + g1) * ak1;
#pragma unroll
        for (int off = 32; off > 0; off >>= 1) v += __shfl_xor(v, off, 64);
        float p = __expf(v + r[d]);
        atomicAdd(out + (size_t)d * D + lane, p * bf2f(xtb[(size_t)s * D + lane]));
        if (lane == 0) atomicAdd(denom + d, p);
    }
}

// ---------------- Kernel 3: normalize + bias ----------------
__global__ __launch_bounds__(256) void fin_kernel(
    float* __restrict__ out, const float* __restrict__ denom,
    const float* __restrict__ bias, int total)
{
    int i = blockIdx.x * 256 + threadIdx.x;
    if (i >= total) return;
    int n = i >> 6, k = i & 63;
    float dn = denom[n];
    float sc = dn > 0.f ? 1.f / dn : 0.f;
    out[i] = fmaf(out[i], sc, bias[k]);
}

extern "C" void kernel_launch(void* const* d_in, const int* in_sizes, int n_in,
                              void* d_out, int out_size, void* d_ws, size_t ws_size,
                              hipStream_t stream)
{
    const float* x         = (const float*)d_in[0];
    const float* edge_attr = (const float*)d_in[1];
    const int*   src       = (const int*)d_in[2];
    const int*   dst       = (const int*)d_in[3];
    const float* W1        = (const float*)d_in[4];
    const float* W2        = (const float*)d_in[5];
    const float* attn      = (const float*)d_in[6];
    const float* bias      = (const float*)d_in[7];
    float* out = (float*)d_out;

    const int N_ = in_sizes[0] / D;   // 100000
    const int E_ = in_sizes[2];       // 1280000

    // workspace: Abf[N*64] bf16 | xtb[N*64] bf16 | r[N] f32 | denom[N] f32
    u16*   Abf   = (u16*)d_ws;
    u16*   xtb   = Abf + (size_t)N_ * D;
    float* r     = (float*)(xtb + (size_t)N_ * D);
    float* denom = r + N_;

    hipMemsetAsync(out,   0, (size_t)out_size * sizeof(float), stream);
    hipMemsetAsync(denom, 0, (size_t)N_ * sizeof(float), stream);

    node_kernel<<<(N_ + 127) / 128, 256, 0, stream>>>(x, W1, W2, Abf, xtb, N_);
    r_kernel<<<1024, 256, 0, stream>>>(x, attn, r, N_);

    const int eBlocks = 8192;
    const int nwaves  = eBlocks * 4;
    const int npairs  = E_ >> 1;
    const int chunk   = (npairs + nwaves - 1) / nwaves;
    edge_kernel<<<eBlocks, 256, 0, stream>>>(edge_attr, src, dst, W1, attn,
                                             Abf, xtb, r, out, denom, E_, chunk);

    fin_kernel<<<((size_t)N_ * D + 255) / 256, 256, 0, stream>>>(out, denom, bias, N_ * D);
}